// Round 2
// baseline (2032.277 us; speedup 1.0000x reference)
//
#include <hip/hip_runtime.h>

// ---------------------------------------------------------------------------
// AttentionLayer: q=XWq+bq, k=XWk+bk, v=XWv+bv; S=qk^T (NO 1/sqrt(d) scale);
// P=softmax(S); out=PV.   B=4, L=4096, D=768, fp32 in/out.
//
// Precision: hi/lo _Float16 split (Markidis) for X,W,Q,K -> logits good to
// ~1e-3 (std~28 unscaled logits; single-half logits would blow the 0.114
// absmax budget on near-tied softmax rows). P,V plain f16.
//
// R2 restructure of k_attn: waves split K-POSITIONS for S (full-D per wave,
// S stays in registers), split D for PV. Only cross-wave traffic: 32 row-max
// + 32 row-sum floats per 128-position tile. 2 barriers per tile (was 3 per
// 32 positions). m/l/alpha maintained redundantly per wave in registers.
// ---------------------------------------------------------------------------

typedef _Float16 f16;
typedef _Float16 f16x8 __attribute__((ext_vector_type(8)));
typedef _Float16 f16x4 __attribute__((ext_vector_type(4)));
typedef float f32x4 __attribute__((ext_vector_type(4)));

#define NB 4
#define NL 4096
#define ND 768
#define NM (NB * NL)  // 16384 rows

__device__ __forceinline__ void split_f16(float v, f16& h, f16& l) {
    h = (f16)v;
    l = (f16)(v - (float)h);
}

// ---- convert hidden_states -> Xh, Xl (hi/lo f16), same [M][D] layout ------
__global__ __launch_bounds__(256) void k_convert_x(
    const float* __restrict__ x, f16* __restrict__ xh, f16* __restrict__ xl) {
    int i = blockIdx.x * 256 + threadIdx.x;       // group of 4 elems
    float4 v = ((const float4*)x)[i];
    float vv[4] = {v.x, v.y, v.z, v.w};
    f16x4 hv, lv;
    for (int j = 0; j < 4; ++j) {
        f16 h, l; split_f16(vv[j], h, l);
        hv[j] = h; lv[j] = l;
    }
    ((f16x4*)xh)[i] = hv;
    ((f16x4*)xl)[i] = lv;
}

// ---- transpose W [k][n] -> Wt [n][k] as hi/lo f16 (3 matrices, z picks) ---
__global__ __launch_bounds__(256) void k_convert_w(
    const float* __restrict__ Wq, const float* __restrict__ Wk,
    const float* __restrict__ Wv, f16* __restrict__ wth, f16* __restrict__ wtl) {
    __shared__ float tile[32][33];
    const float* W = blockIdx.z == 0 ? Wq : (blockIdx.z == 1 ? Wk : Wv);
    f16* th = wth + blockIdx.z * ND * ND;
    f16* tl = wtl + blockIdx.z * ND * ND;
    const int k0 = blockIdx.x * 32, n0 = blockIdx.y * 32;
    const int tx = threadIdx.x & 31, ty = threadIdx.x >> 5;  // ty 0..7
    for (int r = 0; r < 4; ++r)
        tile[r * 8 + ty][tx] = W[(k0 + r * 8 + ty) * ND + n0 + tx];
    __syncthreads();
    for (int r = 0; r < 4; ++r) {
        float v = tile[tx][r * 8 + ty];
        int n = n0 + r * 8 + ty, k = k0 + tx;
        f16 h, l; split_f16(v, h, l);
        th[n * ND + k] = h;
        tl[n * ND + k] = l;
    }
}

// ---- projection GEMM: C[M,N] = X[M,K] * W[K,N] + bias, hi/lo MFMA ---------
// z=0 -> Qh/Ql, z=1 -> Kh/Kl, z=2 -> Vt (transposed [b][d][pos], hi only)
__global__ __launch_bounds__(256, 2) void k_proj(
    const f16* __restrict__ xh, const f16* __restrict__ xl,
    const f16* __restrict__ wth, const f16* __restrict__ wtl,
    const float* __restrict__ bq, const float* __restrict__ bk,
    const float* __restrict__ bv,
    f16* __restrict__ qh, f16* __restrict__ ql,
    f16* __restrict__ kh, f16* __restrict__ kl, f16* __restrict__ vt) {
    const int z = blockIdx.z;
    const f16* wh = wth + z * ND * ND;
    const f16* wl = wtl + z * ND * ND;
    const float* bias = z == 0 ? bq : (z == 1 ? bk : bv);
    const int m0 = blockIdx.x * 128, n0 = blockIdx.y * 128;

    __shared__ f16 Ah[128 * 40], Al[128 * 40], Bh[128 * 40], Bl[128 * 40];

    const int t = threadIdx.x;
    const int lane = t & 63, quad = lane >> 4, l16 = lane & 15;
    const int wave = t >> 6, wm = wave >> 1, wn = wave & 1;

    f32x4 acc[4][4] = {};

    for (int kt = 0; kt < 24; ++kt) {
        const int k0 = kt * 32;
        __syncthreads();
        for (int i = 0; i < 2; ++i) {
            int c = i * 256 + t;
            int row = c >> 2, kc = (c & 3) * 8;
            *(uint4*)&Ah[row * 40 + kc] = *(const uint4*)&xh[(m0 + row) * ND + k0 + kc];
            *(uint4*)&Al[row * 40 + kc] = *(const uint4*)&xl[(m0 + row) * ND + k0 + kc];
            *(uint4*)&Bh[row * 40 + kc] = *(const uint4*)&wh[(n0 + row) * ND + k0 + kc];
            *(uint4*)&Bl[row * 40 + kc] = *(const uint4*)&wl[(n0 + row) * ND + k0 + kc];
        }
        __syncthreads();
        f16x8 ah[4], al[4], bh[4], bl[4];
#pragma unroll
        for (int f = 0; f < 4; ++f) {
            int m = wm * 64 + f * 16 + l16;
            ah[f] = *(const f16x8*)&Ah[m * 40 + quad * 8];
            al[f] = *(const f16x8*)&Al[m * 40 + quad * 8];
            int n = wn * 64 + f * 16 + l16;
            bh[f] = *(const f16x8*)&Bh[n * 40 + quad * 8];
            bl[f] = *(const f16x8*)&Bl[n * 40 + quad * 8];
        }
#pragma unroll
        for (int fm = 0; fm < 4; ++fm)
#pragma unroll
            for (int fn = 0; fn < 4; ++fn) {
                f32x4 c = acc[fm][fn];
                c = __builtin_amdgcn_mfma_f32_16x16x32_f16(al[fm], bh[fn], c, 0, 0, 0);
                c = __builtin_amdgcn_mfma_f32_16x16x32_f16(ah[fm], bl[fn], c, 0, 0, 0);
                c = __builtin_amdgcn_mfma_f32_16x16x32_f16(ah[fm], bh[fn], c, 0, 0, 0);
                acc[fm][fn] = c;
            }
    }
#pragma unroll
    for (int fm = 0; fm < 4; ++fm)
#pragma unroll
        for (int fn = 0; fn < 4; ++fn) {
            int col = n0 + wn * 64 + fn * 16 + l16;
            float bv_ = bias[col];
#pragma unroll
            for (int r = 0; r < 4; ++r) {
                int row = m0 + wm * 64 + fm * 16 + quad * 4 + r;
                float v = acc[fm][fn][r] + bv_;
                f16 h, l; split_f16(v, h, l);
                if (z == 0) { qh[row * ND + col] = h; ql[row * ND + col] = l; }
                else if (z == 1) { kh[row * ND + col] = h; kl[row * ND + col] = l; }
                else {
                    int b = row >> 12, pos = row & 4095;
                    vt[(b * ND + col) * NL + pos] = h;
                }
            }
        }
}

// ---- flash attention, R2 structure --------------------------------------
// Block: 4 waves, Q-tile 32 rows, K-tile 128 positions.
// S phase: wave w owns positions [p0+32w, p0+32w+32), full D=768, S in regs.
// PV phase: wave w owns D-chunk [192w, 192w+192) over all 128 positions.
// Cross-wave LDS: lmax/lsum[4][32] + Pbuf[32][136] f16. 2 barriers/tile.
__global__ __launch_bounds__(256, 2) void k_attn(
    const f16* __restrict__ qh, const f16* __restrict__ ql,
    const f16* __restrict__ kh, const f16* __restrict__ kl,
    const f16* __restrict__ vt, float* __restrict__ out) {
    const int qt = blockIdx.x, b = blockIdx.y;
    const int q0 = qt * 32;
    const int t = threadIdx.x, w = t >> 6, lane = t & 63;
    const int quad = lane >> 4, l16 = lane & 15;
    const int dw = w * 192;

    __shared__ float lmax[4][32], lsum[4][32];
    __shared__ f16 Pbuf[32 * 136];  // row stride 136 f16 = 272 B

    float m_prev[2][4], l_prev[2][4];
#pragma unroll
    for (int fm = 0; fm < 2; ++fm)
#pragma unroll
        for (int r = 0; r < 4; ++r) { m_prev[fm][r] = -1e30f; l_prev[fm][r] = 0.f; }

    f32x4 oacc[2][12] = {};

    const int qbase = (b * NL + q0) * ND;

    for (int kt = 0; kt < 32; ++kt) {
        const int p0 = kt * 128;
        const int pw0 = p0 + w * 32;

        // ---- S = Q K^T for this wave's 32 positions, full D, hi/lo ----
        f32x4 sacc[2][2] = {};
#pragma unroll 3
        for (int dk = 0; dk < 24; ++dk) {
            const int d = dk * 32 + quad * 8;
            f16x8 aH[2], aL[2], bH[2], bL[2];
#pragma unroll
            for (int f = 0; f < 2; ++f) {
                const int qr = qbase + (f * 16 + l16) * ND + d;
                aH[f] = *(const f16x8*)&qh[qr];
                aL[f] = *(const f16x8*)&ql[qr];
                const int kr = (b * NL + pw0 + f * 16 + l16) * ND + d;
                bH[f] = *(const f16x8*)&kh[kr];
                bL[f] = *(const f16x8*)&kl[kr];
            }
#pragma unroll
            for (int fm = 0; fm < 2; ++fm)
#pragma unroll
                for (int fn = 0; fn < 2; ++fn) {
                    f32x4 c = sacc[fm][fn];
                    c = __builtin_amdgcn_mfma_f32_16x16x32_f16(aL[fm], bH[fn], c, 0, 0, 0);
                    c = __builtin_amdgcn_mfma_f32_16x16x32_f16(aH[fm], bL[fn], c, 0, 0, 0);
                    c = __builtin_amdgcn_mfma_f32_16x16x32_f16(aH[fm], bH[fn], c, 0, 0, 0);
                    sacc[fm][fn] = c;
                }
        }

        // ---- wave-local row max over this wave's 32 positions ----
        float rm[2][4];
#pragma unroll
        for (int fm = 0; fm < 2; ++fm)
#pragma unroll
            for (int r = 0; r < 4; ++r)
                rm[fm][r] = fmaxf(sacc[fm][0][r], sacc[fm][1][r]);
#pragma unroll
        for (int off = 1; off < 16; off <<= 1)
#pragma unroll
            for (int fm = 0; fm < 2; ++fm)
#pragma unroll
                for (int r = 0; r < 4; ++r)
                    rm[fm][r] = fmaxf(rm[fm][r], __shfl_xor(rm[fm][r], off, 64));
        if (l16 == 0)
#pragma unroll
            for (int fm = 0; fm < 2; ++fm)
#pragma unroll
                for (int r = 0; r < 4; ++r)
                    lmax[w][fm * 16 + quad * 4 + r] = rm[fm][r];
        __syncthreads();  // B1: lmax visible

        // ---- combine maxes (redundant per wave, register m/l state) ----
        float mn[2][4], al[2][4], ps[2][4];
#pragma unroll
        for (int fm = 0; fm < 2; ++fm)
#pragma unroll
            for (int r = 0; r < 4; ++r) {
                const int row = fm * 16 + quad * 4 + r;
                float g = fmaxf(fmaxf(lmax[0][row], lmax[1][row]),
                                fmaxf(lmax[2][row], lmax[3][row]));
                float m_old = m_prev[fm][r];
                float m_new = fmaxf(m_old, g);
                mn[fm][r] = m_new;
                al[fm][r] = __expf(m_old - m_new);
                m_prev[fm][r] = m_new;
                ps[fm][r] = 0.f;
            }
        // ---- P = exp(S - m), write f16 to Pbuf, accumulate row sums ----
#pragma unroll
        for (int fm = 0; fm < 2; ++fm)
#pragma unroll
            for (int fn = 0; fn < 2; ++fn)
#pragma unroll
                for (int r = 0; r < 4; ++r) {
                    float p = __expf(sacc[fm][fn][r] - mn[fm][r]);
                    ps[fm][r] += p;
                    Pbuf[(fm * 16 + quad * 4 + r) * 136 + w * 32 + fn * 16 + l16] = (f16)p;
                }
#pragma unroll
        for (int off = 1; off < 16; off <<= 1)
#pragma unroll
            for (int fm = 0; fm < 2; ++fm)
#pragma unroll
                for (int r = 0; r < 4; ++r)
                    ps[fm][r] += __shfl_xor(ps[fm][r], off, 64);
        if (l16 == 0)
#pragma unroll
            for (int fm = 0; fm < 2; ++fm)
#pragma unroll
                for (int r = 0; r < 4; ++r)
                    lsum[w][fm * 16 + quad * 4 + r] = ps[fm][r];
        __syncthreads();  // B2: Pbuf + lsum visible

        // ---- l update + O rescale + PV over this wave's 192 D-cols ----
#pragma unroll
        for (int fm = 0; fm < 2; ++fm)
#pragma unroll
            for (int r = 0; r < 4; ++r) {
                const int row = fm * 16 + quad * 4 + r;
                l_prev[fm][r] = al[fm][r] * l_prev[fm][r] +
                                (lsum[0][row] + lsum[1][row] + lsum[2][row] + lsum[3][row]);
            }
#pragma unroll
        for (int fm = 0; fm < 2; ++fm)
#pragma unroll
            for (int fn = 0; fn < 12; ++fn)
#pragma unroll
                for (int r = 0; r < 4; ++r)
                    oacc[fm][fn][r] *= al[fm][r];

#pragma unroll
        for (int kk = 0; kk < 4; ++kk) {
            f16x8 pa[2];
#pragma unroll
            for (int fm = 0; fm < 2; ++fm)
                pa[fm] = *(const f16x8*)&Pbuf[(fm * 16 + l16) * 136 + kk * 32 + quad * 8];
            f16x8 vb[12];
#pragma unroll
            for (int fn = 0; fn < 12; ++fn) {
                const int dcol = dw + fn * 16 + l16;
                vb[fn] = *(const f16x8*)&vt[(b * ND + dcol) * NL + p0 + kk * 32 + quad * 8];
            }
#pragma unroll
            for (int fn = 0; fn < 12; ++fn)
#pragma unroll
                for (int fm = 0; fm < 2; ++fm)
                    oacc[fm][fn] = __builtin_amdgcn_mfma_f32_16x16x32_f16(pa[fm], vb[fn], oacc[fm][fn], 0, 0, 0);
        }
        // no barrier here: next tile's Pbuf/lmax writes are fenced by B1/B2
    }

    // ---- epilogue: out = O / l ----
#pragma unroll
    for (int fm = 0; fm < 2; ++fm) {
        float linv[4];
#pragma unroll
        for (int r = 0; r < 4; ++r) linv[r] = 1.f / l_prev[fm][r];
#pragma unroll
        for (int fn = 0; fn < 12; ++fn) {
            const int col = dw + fn * 16 + l16;
#pragma unroll
            for (int r = 0; r < 4; ++r) {
                const int row = b * NL + q0 + fm * 16 + quad * 4 + r;
                out[row * ND + col] = oacc[fm][fn][r] * linv[r];
            }
        }
    }
}

extern "C" void kernel_launch(void* const* d_in, const int* in_sizes, int n_in,
                              void* d_out, int out_size, void* d_ws, size_t ws_size,
                              hipStream_t stream) {
    const float* hs = (const float*)d_in[0];
    const float* Wq = (const float*)d_in[1];
    const float* bq = (const float*)d_in[2];
    const float* Wk = (const float*)d_in[3];
    const float* bk = (const float*)d_in[4];
    const float* Wv = (const float*)d_in[5];
    const float* bv = (const float*)d_in[6];
    float* out = (float*)d_out;

    char* ws = (char*)d_ws;
    size_t off = 0;
    auto alloc = [&](size_t bytes) {
        void* p = ws + off;
        off += (bytes + 255) & ~(size_t)255;
        return p;
    };
    const size_t MD = (size_t)NM * ND;
    f16* Xh = (f16*)alloc(MD * 2);
    f16* Xl = (f16*)alloc(MD * 2);
    f16* Wth = (f16*)alloc((size_t)3 * ND * ND * 2);
    f16* Wtl = (f16*)alloc((size_t)3 * ND * ND * 2);
    f16* Qh = (f16*)alloc(MD * 2);
    f16* Ql = (f16*)alloc(MD * 2);
    f16* Kh = (f16*)alloc(MD * 2);
    f16* Kl = (f16*)alloc(MD * 2);
    f16* Vt = (f16*)alloc(MD * 2);
    (void)ws_size; (void)in_sizes; (void)n_in; (void)out_size;

    k_convert_x<<<dim3(MD / 1024), 256, 0, stream>>>(hs, Xh, Xl);
    k_convert_w<<<dim3(24, 24, 3), 256, 0, stream>>>(Wq, Wk, Wv, Wth, Wtl);
    k_proj<<<dim3(NM / 128, ND / 128, 3), 256, 0, stream>>>(
        Xh, Xl, Wth, Wtl, bq, bk, bv, Qh, Ql, Kh, Kl, Vt);
    k_attn<<<dim3(NL / 32, NB), 256, 0, stream>>>(Qh, Ql, Kh, Kl, Vt, out);
}